// Round 4
// baseline (415.971 us; speedup 1.0000x reference)
//
#include <hip/hip_runtime.h>

// Sizes fixed by the problem.
#define TT 1653          // T
#define DD 512           // D
#define BB 2             // B
#define DE 64            // D/E
#define BEH 16           // B*E
#define TTILES 26        // ceil(T/64)
#define TPAD 1664        // T padded to multiple of 64
#define SQN 26           // ovt s-tiles (TPAD/64)
#define NJC 8            // ovt j-split (was 4): 3328 blocks, 3-4 tiles each
#define SCN 4            // attn s-split: 1664 blocks, 6-7 tiles each
#define MPSTRIDE TPAD    // Mpart row stride (floats)
#define HSTRIDE ((size_t)BB * TT * DD)   // Hpart partial stride (floats)

typedef __attribute__((ext_vector_type(8))) short bf16x8;   // 8 bf16 (4 VGPRs)
typedef __attribute__((ext_vector_type(4))) float f32x4;
typedef float f32x4u  __attribute__((ext_vector_type(4), aligned(4)));  // O rows only 4B-aligned (TT odd)

__device__ __forceinline__ short f2bf(float f) {
    union { float f; unsigned u; } v; v.f = f;
    unsigned r = v.u + 0x7fffu + ((v.u >> 16) & 1u);   // RNE
    return (short)(r >> 16);
}
__device__ __forceinline__ unsigned pack2(float a, float b) {
    return (unsigned)(unsigned short)f2bf(a) | ((unsigned)(unsigned short)f2bf(b) << 16);
}
__device__ __forceinline__ float bf2f(short s) {
    union { unsigned u; float f; } v; v.u = ((unsigned)(unsigned short)s) << 16;
    return v.f;
}

// Raw barriers (no vmcnt drain); compiler emits counted vmcnt at reg uses.
__device__ __forceinline__ void bar_fenced() {
    __builtin_amdgcn_sched_barrier(0);
    __builtin_amdgcn_s_barrier();
    __builtin_amdgcn_sched_barrier(0);
}
__device__ __forceinline__ void lgkm0_bar() {
    asm volatile("s_waitcnt lgkmcnt(0)" ::: "memory");
    __builtin_amdgcn_sched_barrier(0);
    __builtin_amdgcn_s_barrier();
    __builtin_amdgcn_sched_barrier(0);
}

// ---------------------------------------------------------------------------
// Kernel 0: punish matrix -> bf16 [T][TPAD], zero pad cols.
// ---------------------------------------------------------------------------
__global__ __launch_bounds__(256) void convp2_kernel(
    const float* __restrict__ P, short* __restrict__ Pbf)
{
    const int g = blockIdx.x * 256 + threadIdx.x;
    const int NG4 = TPAD / 4;                       // 416
    if (g >= TT * NG4) return;
    const int r = g / NG4, c4 = (g - r * NG4) * 4;
    float p0 = 0.f, p1 = 0.f, p2 = 0.f, p3 = 0.f;
    const float* prow = P + (size_t)r * TT;
    if (c4 + 0 < TT) p0 = prow[c4 + 0];
    if (c4 + 1 < TT) p1 = prow[c4 + 1];
    if (c4 + 2 < TT) p2 = prow[c4 + 2];
    if (c4 + 3 < TT) p3 = prow[c4 + 3];
    uint2 o; o.x = pack2(p0, p1); o.y = pack2(p2, p3);
    *(uint2*)(Pbf + (size_t)r * TPAD + c4) = o;
}

// ---------------------------------------------------------------------------
// Kernel 1 (MFMA): projections Q/K/V in [B, D, T] scramble layout, bf16 out.
// v5: 2-deep register staging, raw barriers.
// ---------------------------------------------------------------------------
struct PStage { float4 w0, w1, w2, w3, x0, x1, x2, x3; };

__global__ __launch_bounds__(256) void proj5_kernel(
    const float* __restrict__ X,
    const float* __restrict__ W0, const float* __restrict__ b0,
    const float* __restrict__ W1, const float* __restrict__ b1,
    const float* __restrict__ W2, const float* __restrict__ b2,
    short* __restrict__ Y0, short* __restrict__ Y1, short* __restrict__ Y2)
{
    __shared__ __align__(16) short Wsh[64][72];  // [d][k] bf16
    __shared__ __align__(16) short Xs[64][72];   // [t][k] bf16

    const int tt = blockIdx.x, dt = blockIdx.y, z = blockIdx.z;
    const int b = z / 3, which = z % 3;
    const float* W    = (which == 0) ? W0 : (which == 1) ? W1 : W2;
    const float* bias = (which == 0) ? b0 : (which == 1) ? b1 : b2;
    short* Y          = (which == 0) ? Y0 : (which == 1) ? Y1 : Y2;

    const int t0 = tt * 64, d0 = dt * 64;
    const float* Xb = X + (size_t)b * TT * DD;

    const int tid  = threadIdx.x;
    const int wave = tid >> 6, lane = tid & 63;
    const int quad = lane >> 4, l16 = lane & 15;
    const int srow = tid >> 2, scg = (tid & 3) * 16;
    const int trow = t0 + srow;
    const int rx = min(trow, TT - 1);

    f32x4 acc[4];
    #pragma unroll
    for (int i = 0; i < 4; ++i) acc[i] = (f32x4){0.f, 0.f, 0.f, 0.f};

    auto stage = [&](PStage& S, int k0) {
        const float* wrow = W + (size_t)(d0 + srow) * DD + k0 + scg;
        S.w0 = *(const float4*)(wrow);
        S.w1 = *(const float4*)(wrow + 4);
        S.w2 = *(const float4*)(wrow + 8);
        S.w3 = *(const float4*)(wrow + 12);
        const float* xrow = Xb + (size_t)rx * DD + k0 + scg;
        S.x0 = *(const float4*)(xrow);
        S.x1 = *(const float4*)(xrow + 4);
        S.x2 = *(const float4*)(xrow + 8);
        S.x3 = *(const float4*)(xrow + 12);
    };
    auto lds_write = [&](const PStage& S) {
        const bool tv = (trow < TT);
        float4 zz = make_float4(0.f, 0.f, 0.f, 0.f);
        float4 y0 = tv ? S.x0 : zz, y1 = tv ? S.x1 : zz;
        float4 y2 = tv ? S.x2 : zz, y3 = tv ? S.x3 : zz;
        uint4 pw0, pw1, px0, px1;
        pw0.x = pack2(S.w0.x, S.w0.y); pw0.y = pack2(S.w0.z, S.w0.w);
        pw0.z = pack2(S.w1.x, S.w1.y); pw0.w = pack2(S.w1.z, S.w1.w);
        pw1.x = pack2(S.w2.x, S.w2.y); pw1.y = pack2(S.w2.z, S.w2.w);
        pw1.z = pack2(S.w3.x, S.w3.y); pw1.w = pack2(S.w3.z, S.w3.w);
        px0.x = pack2(y0.x, y0.y); px0.y = pack2(y0.z, y0.w);
        px0.z = pack2(y1.x, y1.y); px0.w = pack2(y1.z, y1.w);
        px1.x = pack2(y2.x, y2.y); px1.y = pack2(y2.z, y2.w);
        px1.z = pack2(y3.x, y3.y); px1.w = pack2(y3.z, y3.w);
        *(uint4*)&Wsh[srow][scg]     = pw0;
        *(uint4*)&Wsh[srow][scg + 8] = pw1;
        *(uint4*)&Xs[srow][scg]      = px0;
        *(uint4*)&Xs[srow][scg + 8]  = px1;
    };
    auto mfma_tile = [&]() {
        #pragma unroll
        for (int ks = 0; ks < 2; ++ks) {
            bf16x8 a = *(const bf16x8*)&Wsh[wave * 16 + l16][ks * 32 + quad * 8];
            #pragma unroll
            for (int nt = 0; nt < 4; ++nt) {
                bf16x8 bb = *(const bf16x8*)&Xs[nt * 16 + l16][ks * 32 + quad * 8];
                acc[nt] = __builtin_amdgcn_mfma_f32_16x16x32_bf16(a, bb, acc[nt], 0, 0, 0);
            }
        }
    };

    PStage sA, sB;
    stage(sA, 0);
    stage(sB, 64);
    for (int k0 = 0; k0 < DD; k0 += 128) {   // 8 iters -> 4 pairs
        lds_write(sA);
        if (k0 + 128 < DD) stage(sA, k0 + 128);
        lgkm0_bar();
        mfma_tile();
        bar_fenced();
        lds_write(sB);
        if (k0 + 192 < DD) stage(sB, k0 + 192);
        lgkm0_bar();
        mfma_tile();
        bar_fenced();
    }

    #pragma unroll
    for (int nt = 0; nt < 4; ++nt) {
        const int t = t0 + nt * 16 + l16;
        if (t < TT) {
            #pragma unroll
            for (int r = 0; r < 4; ++r) {
                const int d = d0 + wave * 16 + quad * 4 + r;
                float v = acc[nt][r] + bias[d];
                if (which < 2) v = 1.2f / (1.0f + __expf(-1.6f * v));
                Y[((size_t)b * DD + d) * TT + t] = f2bf(v);
            }
        }
    }
}

// ---------------------------------------------------------------------------
// Kernel 2 (MFMA): partial Mt. v7 — NJC 8 (halved per-block serial chain).
//   Mpart[jc][be][d][s] = sum_{j in chunk jc} V[j][d] * O[j][s]
// ---------------------------------------------------------------------------
struct OVStage {
    f32x4u o0a, o0b, o1a, o1b;    // O rows j0+2p, +1, +32, +33 ; cols 4sc..+3
    uint2  v0a, v0b, v1a, v1b;    // V same rows (raw, clamped)
};

__global__ __launch_bounds__(256) void ovt7_kernel(
    const float* __restrict__ orth, const short* __restrict__ Vb,
    float* __restrict__ Mpart)
{
    __shared__ __align__(16) short Os[64][72];  // [s_local][j_local] bf16
    __shared__ __align__(16) short Vs[64][72];  // [d][j_local] bf16

    const int sq = blockIdx.x, be = blockIdx.y, jc = blockIdx.z;
    const int s0 = sq * 64;
    // 26 tiles over 8 chunks: {4,4,3,3,3,3,3,3}
    const int jt0 = (jc < 2) ? jc * 4 : 8 + (jc - 2) * 3;
    const int jtn = (jc < 2) ? 4 : 3;

    const float* O  = orth + (size_t)be * TT * TT;
    const short* Vh = Vb + (size_t)be * DE * TT;

    const int tid  = threadIdx.x;
    const int wave = tid >> 6, lane = tid & 63;
    const int quad = lane >> 4, l16 = lane & 15;

    const int p  = tid & 15;
    const int sc = tid >> 4;
    const int ca = s0 + 4 * sc;
    const bool fastS = (s0 + 64 <= TT);

    f32x4 acc[4];
    #pragma unroll
    for (int i = 0; i < 4; ++i) acc[i] = (f32x4){0.f, 0.f, 0.f, 0.f};

    auto stage_load = [&](OVStage& S, int j0) {
        const int jA = j0 + 2 * p;
        const int r0  = min(jA,      TT - 1);
        const int r0b = min(jA + 1,  TT - 1);
        const int r1  = min(jA + 32, TT - 1);
        const int r1b = min(jA + 33, TT - 1);
        if (fastS) {
            S.o0a = *(const f32x4u*)(O + (size_t)r0  * TT + ca);
            S.o0b = *(const f32x4u*)(O + (size_t)r0b * TT + ca);
            S.o1a = *(const f32x4u*)(O + (size_t)r1  * TT + ca);
            S.o1b = *(const f32x4u*)(O + (size_t)r1b * TT + ca);
        } else {
            #pragma unroll
            for (int i = 0; i < 4; ++i) {
                const int col = ca + i;
                const bool cv = (col < TT);
                S.o0a[i] = cv ? O[(size_t)r0  * TT + col] : 0.f;
                S.o0b[i] = cv ? O[(size_t)r0b * TT + col] : 0.f;
                S.o1a[i] = cv ? O[(size_t)r1  * TT + col] : 0.f;
                S.o1b[i] = cv ? O[(size_t)r1b * TT + col] : 0.f;
            }
        }
        S.v0a = *(const uint2*)(Vh + (size_t)r0  * DE + 4 * sc);
        S.v0b = *(const uint2*)(Vh + (size_t)r0b * DE + 4 * sc);
        S.v1a = *(const uint2*)(Vh + (size_t)r1  * DE + 4 * sc);
        S.v1b = *(const uint2*)(Vh + (size_t)r1b * DE + 4 * sc);
    };

    auto lds_write = [&](const OVStage& S, int j0) {
        const int jA = j0 + 2 * p;
        #pragma unroll
        for (int i = 0; i < 4; ++i) {
            *(unsigned*)&Os[4 * sc + i][2 * p]      = pack2(S.o0a[i], S.o0b[i]);
            *(unsigned*)&Os[4 * sc + i][2 * p + 32] = pack2(S.o1a[i], S.o1b[i]);
        }
        const uint2 z = make_uint2(0u, 0u);
        uint2 v0a = (jA      < TT) ? S.v0a : z;
        uint2 v0b = (jA + 1  < TT) ? S.v0b : z;
        uint2 v1a = (jA + 32 < TT) ? S.v1a : z;
        uint2 v1b = (jA + 33 < TT) ? S.v1b : z;
        *(unsigned*)&Vs[4 * sc + 0][2 * p]      = (v0a.x & 0xffffu) | (v0b.x << 16);
        *(unsigned*)&Vs[4 * sc + 1][2 * p]      = (v0a.x >> 16)     | (v0b.x & 0xffff0000u);
        *(unsigned*)&Vs[4 * sc + 2][2 * p]      = (v0a.y & 0xffffu) | (v0b.y << 16);
        *(unsigned*)&Vs[4 * sc + 3][2 * p]      = (v0a.y >> 16)     | (v0b.y & 0xffff0000u);
        *(unsigned*)&Vs[4 * sc + 0][2 * p + 32] = (v1a.x & 0xffffu) | (v1b.x << 16);
        *(unsigned*)&Vs[4 * sc + 1][2 * p + 32] = (v1a.x >> 16)     | (v1b.x & 0xffff0000u);
        *(unsigned*)&Vs[4 * sc + 2][2 * p + 32] = (v1a.y & 0xffffu) | (v1b.y << 16);
        *(unsigned*)&Vs[4 * sc + 3][2 * p + 32] = (v1a.y >> 16)     | (v1b.y & 0xffff0000u);
    };

    auto mfma_tile = [&]() {
        #pragma unroll
        for (int ks = 0; ks < 2; ++ks) {
            bf16x8 bb = *(const bf16x8*)&Os[wave * 16 + l16][ks * 32 + quad * 8];
            #pragma unroll
            for (int i = 0; i < 4; ++i) {
                bf16x8 a = *(const bf16x8*)&Vs[i * 16 + l16][ks * 32 + quad * 8];
                acc[i] = __builtin_amdgcn_mfma_f32_16x16x32_bf16(a, bb, acc[i], 0, 0, 0);
            }
        }
    };

    OVStage sA, sB;
    stage_load(sA, (jt0 + 0) * 64);
    stage_load(sB, (jt0 + 1) * 64);

    for (int t = 0; t < jtn; t += 2) {
        lds_write(sA, (jt0 + t) * 64);
        if (t + 2 < jtn) stage_load(sA, (jt0 + t + 2) * 64);
        lgkm0_bar();
        mfma_tile();
        bar_fenced();
        if (t + 1 < jtn) {
            lds_write(sB, (jt0 + t + 1) * 64);
            if (t + 3 < jtn) stage_load(sB, (jt0 + t + 3) * 64);
            lgkm0_bar();
            mfma_tile();
            bar_fenced();
        }
    }

    float* Mp = Mpart + (size_t)(jc * BEH + be) * DE * MPSTRIDE;
    const int s = s0 + wave * 16 + l16;
    #pragma unroll
    for (int i = 0; i < 4; ++i) {
        #pragma unroll
        for (int r = 0; r < 4; ++r) {
            const int d = i * 16 + quad * 4 + r;
            Mp[(size_t)d * MPSTRIDE + s] = acc[i][r];
        }
    }
}

// ---------------------------------------------------------------------------
// Kernel 2b: reduce the 8 j-chunk partials -> bf16 Mt[be][d][TPAD].
// ---------------------------------------------------------------------------
__global__ __launch_bounds__(256) void mreduce_kernel(
    const float* __restrict__ Mpart, short* __restrict__ Mt)
{
    const int g = blockIdx.x * 256 + threadIdx.x;
    const int NG = TPAD / 4;                        // 416
    if (g >= BEH * DE * NG) return;
    const int bd = g / NG;
    const int s4 = (g - bd * NG) * 4;

    const size_t jstride = (size_t)BEH * DE * MPSTRIDE;
    const float* p = Mpart + (size_t)bd * MPSTRIDE + s4;
    float s0 = 0.f, s1 = 0.f, s2 = 0.f, s3 = 0.f;
    #pragma unroll
    for (int j = 0; j < NJC; ++j) {
        float4 a = *(const float4*)(p + j * jstride);
        s0 += a.x; s1 += a.y; s2 += a.z; s3 += a.w;
    }

    uint2 o;
    o.x = pack2(s0, s1);
    o.y = pack2(s2, s3);
    *(uint2*)(Mt + (size_t)bd * TPAD + s4) = o;
}

// ---------------------------------------------------------------------------
// Kernel 3 (MFMA): fused attention. v5 — s-split x4 over blockIdx.z:
// out partial over the chunk's s-tiles (associative), fp32 Hpart, then
// hreduce sums. 416 -> 1664 blocks; 26 -> 6-7 tiles per block.
// ---------------------------------------------------------------------------
struct AStage {
    uint4 k0, k1, m0, m1, p0, p1;
};

__global__ __launch_bounds__(256) void attn5_kernel(
    const short* __restrict__ Qb, const short* __restrict__ Kb,
    const short* __restrict__ Mt, const short* __restrict__ Pbf,
    float* __restrict__ Hpart)
{
    __shared__ __align__(16) short Qs[64][72];  // [i][d]
    __shared__ __align__(16) short Ks[64][72];  // [s][d]
    __shared__ __align__(16) short Ms[64][72];  // [d][s]
    __shared__ __align__(16) short Ps[64][72];  // [i][s]: punish tile, then Wl

    const int it = blockIdx.x, be = blockIdx.y, sch = blockIdx.z;
    const int b = be >> 3, e = be & 7;
    const int i0 = it * 64;
    // 26 s-tiles over 4 chunks: {7,7,6,6}
    const int st0 = (sch < 2) ? sch * 7 : 14 + (sch - 2) * 6;
    const int stn = (sch < 2) ? 7 : 6;

    const short* Qh = Qb + (size_t)be * DE * TT;
    const short* Kh = Kb + (size_t)be * DE * TT;
    const short* Mh = Mt + (size_t)be * DE * TPAD;

    const int tid  = threadIdx.x;
    const int wave = tid >> 6, lane = tid & 63;
    const int quad = lane >> 4, l16 = lane & 15;

    const float invs = 0.024598297f;  // 1/sqrt(1653)

    const int srow = tid >> 2, scg = (tid & 3) * 16;
    const int gi = i0 + srow;
    const bool giv = (gi < TT);
    const int ri = min(gi, TT - 1);

    {   // Q: staged once
        uint4 z = make_uint4(0u, 0u, 0u, 0u);
        uint4 v0 = *(const uint4*)(Qh + (size_t)ri * DE + scg);
        uint4 v1 = *(const uint4*)(Qh + (size_t)ri * DE + scg + 8);
        if (!giv) { v0 = z; v1 = z; }
        *(uint4*)&Qs[srow][scg]     = v0;
        *(uint4*)&Qs[srow][scg + 8] = v1;
    }

    f32x4 out[4];
    #pragma unroll
    for (int i = 0; i < 4; ++i) out[i] = (f32x4){0.f, 0.f, 0.f, 0.f};

    auto stage_regs = [&](AStage& S, int s0) {
        const int gs = s0 + srow;
        const int rs = min(gs, TT - 1);
        S.k0 = *(const uint4*)(Kh + (size_t)rs * DE + scg);
        S.k1 = *(const uint4*)(Kh + (size_t)rs * DE + scg + 8);
        S.m0 = *(const uint4*)(Mh + (size_t)srow * TPAD + s0 + scg);
        S.m1 = *(const uint4*)(Mh + (size_t)srow * TPAD + s0 + scg + 8);
        S.p0 = *(const uint4*)(Pbf + (size_t)ri * TPAD + s0 + scg);
        S.p1 = *(const uint4*)(Pbf + (size_t)ri * TPAD + s0 + scg + 8);
    };

    auto lds_write = [&](const AStage& S, int s0) {
        const int gs = s0 + srow;
        const uint4 z = make_uint4(0u, 0u, 0u, 0u);
        const bool kv = (gs < TT);
        uint4 k0 = kv ? S.k0 : z, k1 = kv ? S.k1 : z;
        uint4 p0 = giv ? S.p0 : z, p1 = giv ? S.p1 : z;
        *(uint4*)&Ks[srow][scg]     = k0;
        *(uint4*)&Ks[srow][scg + 8] = k1;
        *(uint4*)&Ms[srow][scg]     = S.m0;
        *(uint4*)&Ms[srow][scg + 8] = S.m1;
        *(uint4*)&Ps[srow][scg]     = p0;
        *(uint4*)&Ps[srow][scg + 8] = p1;
    };

    auto compute = [&]() {
        f32x4 w[4];
        #pragma unroll
        for (int i = 0; i < 4; ++i) w[i] = (f32x4){0.f, 0.f, 0.f, 0.f};
        #pragma unroll
        for (int ks = 0; ks < 2; ++ks) {
            bf16x8 a = *(const bf16x8*)&Qs[wave * 16 + l16][ks * 32 + quad * 8];
            #pragma unroll
            for (int stile = 0; stile < 4; ++stile) {
                bf16x8 bb = *(const bf16x8*)&Ks[stile * 16 + l16][ks * 32 + quad * 8];
                w[stile] = __builtin_amdgcn_mfma_f32_16x16x32_bf16(a, bb, w[stile], 0, 0, 0);
            }
        }
        #pragma unroll
        for (int stile = 0; stile < 4; ++stile) {
            const int sl = stile * 16 + l16;
            #pragma unroll
            for (int r = 0; r < 4; ++r) {
                const int il = wave * 16 + quad * 4 + r;
                float v = w[stile][r] * invs * bf2f(Ps[il][sl]);
                Ps[il][sl] = f2bf(v);
            }
        }
        #pragma unroll
        for (int ks = 0; ks < 2; ++ks) {
            bf16x8 a = *(const bf16x8*)&Ps[wave * 16 + l16][ks * 32 + quad * 8];
            #pragma unroll
            for (int dt = 0; dt < 4; ++dt) {
                bf16x8 bb = *(const bf16x8*)&Ms[dt * 16 + l16][ks * 32 + quad * 8];
                out[dt] = __builtin_amdgcn_mfma_f32_16x16x32_bf16(a, bb, out[dt], 0, 0, 0);
            }
        }
    };

    AStage sA, sB;
    stage_regs(sA, (st0 + 0) * 64);
    stage_regs(sB, (st0 + 1) * 64);
    lgkm0_bar();   // Qs visible; sA/sB loads stay in flight

    for (int t = 0; t < stn; t += 2) {
        lds_write(sA, (st0 + t) * 64);
        if (t + 2 < stn) stage_regs(sA, (st0 + t + 2) * 64);
        lgkm0_bar();
        compute();
        bar_fenced();
        if (t + 1 < stn) {
            lds_write(sB, (st0 + t + 1) * 64);
            if (t + 3 < stn) stage_regs(sB, (st0 + t + 3) * 64);
            lgkm0_bar();
            compute();
            bar_fenced();
        }
    }

    float* Hp = Hpart + (size_t)sch * HSTRIDE;
    #pragma unroll
    for (int dt = 0; dt < 4; ++dt) {
        const int d = dt * 16 + l16;
        #pragma unroll
        for (int r = 0; r < 4; ++r) {
            const int go = i0 + wave * 16 + quad * 4 + r;
            if (go < TT)
                Hp[((size_t)b * TT + go) * DD + e * 64 + d] = out[dt][r];
        }
    }
}

// ---------------------------------------------------------------------------
// Kernel 3b: sum the 4 attn s-chunk partials -> fp32 Hbuf.
// ---------------------------------------------------------------------------
__global__ __launch_bounds__(256) void hreduce_kernel(
    const float* __restrict__ Hpart, float* __restrict__ Hbuf)
{
    const int g = blockIdx.x * 256 + threadIdx.x;
    const size_t n4 = HSTRIDE / 4;
    if ((size_t)g >= n4) return;
    const size_t off = (size_t)g * 4;
    float4 a0 = *(const float4*)(Hpart + off);
    float4 a1 = *(const float4*)(Hpart + HSTRIDE + off);
    float4 a2 = *(const float4*)(Hpart + 2 * HSTRIDE + off);
    float4 a3 = *(const float4*)(Hpart + 3 * HSTRIDE + off);
    float4 o;
    o.x = a0.x + a1.x + a2.x + a3.x;
    o.y = a0.y + a1.y + a2.y + a3.y;
    o.z = a0.z + a1.z + a2.z + a3.z;
    o.w = a0.w + a1.w + a2.w + a3.w;
    *(float4*)(Hbuf + off) = o;
}

// ---------------------------------------------------------------------------
// Kernel 4: final projection (fp32 SGEMM). v2 — split-k x2 (832 blocks) +
// 2-deep register prefetch with raw barriers (was 3 syncthreads x 32 iters).
// ---------------------------------------------------------------------------
struct OStage { float4 h, w; };

__global__ __launch_bounds__(256) void oproj2_kernel(
    const float* __restrict__ H, const float* __restrict__ Wo,
    float* __restrict__ opart)
{
    __shared__ float Hs[16][68];
    __shared__ float Ns[16][68];

    const int tt = blockIdx.x, nt = blockIdx.y, z = blockIdx.z;
    const int b = z & 1, h = z >> 1;
    const int t0 = tt * 64, n0 = nt * 64;
    const int kbase = h * 256;               // k-chunk [kbase, kbase+256)
    const float* Hb = H + (size_t)b * TT * DD;

    const int tid = threadIdx.x;
    const int tx = tid & 15, ty = tid >> 4;
    const int lrow = tid >> 2, lq = tid & 3;
    const int trow = t0 + lrow;
    const int rx = min(trow, TT - 1);

    float acc[4][4] = {};

    auto stage = [&](OStage& S, int k0) {
        S.h = *(const float4*)(Hb + (size_t)rx * DD + k0 + lq * 4);
        S.w = *(const float4*)(Wo + (size_t)(n0 + lrow) * DD + k0 + lq * 4);
    };
    auto lds_write = [&](const OStage& S) {
        float4 hv = (trow < TT) ? S.h : make_float4(0.f, 0.f, 0.f, 0.f);
        Hs[lq*4+0][lrow] = hv.x; Hs[lq*4+1][lrow] = hv.y;
        Hs[lq*4+2][lrow] = hv.z; Hs[lq*4+3][lrow] = hv.w;
        Ns[lq*4+0][lrow] = S.w.x; Ns[lq*4+1][lrow] = S.w.y;
        Ns[lq*4+2][lrow] = S.w.z; Ns[lq*4+3][lrow] = S.w.w;
    };
    auto compute = [&]() {
        #pragma unroll
        for (int k = 0; k < 16; ++k) {
            float4 a4 = *(const float4*)(&Hs[k][ty*4]);
            float4 c4 = *(const float4*)(&Ns[k][tx*4]);
            float a[4] = {a4.x, a4.y, a4.z, a4.w};
            float c[4] = {c4.x, c4.y, c4.z, c4.w};
            #pragma unroll
            for (int i = 0; i < 4; ++i)
                #pragma unroll
                for (int j = 0; j < 4; ++j)
                    acc[i][j] = fmaf(a[i], c[j], acc[i][j]);
        }
    };

    OStage sA, sB;
    stage(sA, kbase);
    stage(sB, kbase + 16);
    for (int k0 = 0; k0 < 256; k0 += 32) {   // 16 iters -> 8 pairs
        lds_write(sA);
        if (k0 + 32 < 256) stage(sA, kbase + k0 + 32);
        lgkm0_bar();
        compute();
        bar_fenced();
        lds_write(sB);
        if (k0 + 48 < 256) stage(sB, kbase + k0 + 48);
        lgkm0_bar();
        compute();
        bar_fenced();
    }

    float* op = opart + (size_t)h * HSTRIDE;
    #pragma unroll
    for (int i = 0; i < 4; ++i) {
        const int t = t0 + ty*4 + i;
        if (t < TT) {
            float4 v;
            v.x = acc[i][0]; v.y = acc[i][1]; v.z = acc[i][2]; v.w = acc[i][3];
            *(float4*)(op + ((size_t)b * TT + t) * DD + n0 + tx*4) = v;
        }
    }
}

// ---------------------------------------------------------------------------
// Kernel 4b: sum the 2 split-k partials + bias -> out.
// ---------------------------------------------------------------------------
__global__ __launch_bounds__(256) void oreduce_kernel(
    const float* __restrict__ opart, const float* __restrict__ bo,
    float* __restrict__ out)
{
    const int g = blockIdx.x * 256 + threadIdx.x;
    const size_t n4 = HSTRIDE / 4;
    if ((size_t)g >= n4) return;
    const size_t off = (size_t)g * 4;
    const int n0 = (int)(off % DD);
    float4 a0 = *(const float4*)(opart + off);
    float4 a1 = *(const float4*)(opart + HSTRIDE + off);
    float4 bv = *(const float4*)(bo + n0);
    float4 o;
    o.x = a0.x + a1.x + bv.x;
    o.y = a0.y + a1.y + bv.y;
    o.z = a0.z + a1.z + bv.z;
    o.w = a0.w + a1.w + bv.w;
    *(float4*)(out + off) = o;
}

// ---------------------------------------------------------------------------
extern "C" void kernel_launch(void* const* d_in, const int* in_sizes, int n_in,
                              void* d_out, int out_size, void* d_ws, size_t ws_size,
                              hipStream_t stream)
{
    (void)in_sizes; (void)n_in; (void)out_size; (void)ws_size;

    const float* X    = (const float*)d_in[0];
    const float* Wq   = (const float*)d_in[1];
    const float* bq   = (const float*)d_in[2];
    const float* Wk   = (const float*)d_in[3];
    const float* bk   = (const float*)d_in[4];
    const float* Wv   = (const float*)d_in[5];
    const float* bv   = (const float*)d_in[6];
    const float* Wo   = (const float*)d_in[7];
    const float* bo   = (const float*)d_in[8];
    const float* P    = (const float*)d_in[9];
    const float* orth = (const float*)d_in[10];
    float* out = (float*)d_out;

    // Workspace layout (~94 MB):
    //   Qb/Kb/Vb bf16 [B*D*T]          3 x 3,385,344 B
    //   Mtb      bf16 [BE*64*TPAD]         3,407,872 B
    //   Pbf      bf16 [T*TPAD]             5,501,184 B
    //   Hbuf     fp32 [B*T*D]              6,770,688 B
    //   opart    fp32 [2][B*T*D]          13,541,376 B
    //   Mpart    fp32 [8][BE*64][TPAD]    54,525,952 B  (dead after mreduce)
    //   Hpart    fp32 [4][B*T*D]  -- ALIASES Mpart (attn runs after mreduce)
    char* ws = (char*)d_ws;
    const size_t SZH = (size_t)BB * DD * TT * sizeof(short);
    const size_t SZMT = (size_t)BEH * DE * TPAD * sizeof(short);
    const size_t SZP  = (size_t)TT * TPAD * sizeof(short);
    short* Qb  = (short*)(ws);
    short* Kb  = (short*)(ws + SZH);
    short* Vb  = (short*)(ws + 2 * SZH);
    short* Mtb = (short*)(ws + 3 * SZH);
    short* Pbf = (short*)(ws + 3 * SZH + SZMT);
    char*  base1 = ws + 3 * SZH + SZMT + SZP;
    float* Hbuf  = (float*)base1;
    float* opart = (float*)(base1 + HSTRIDE * sizeof(float));
    char*  base2 = base1 + 3 * HSTRIDE * sizeof(float);
    float* Mpart = (float*)base2;
    float* Hpart = (float*)base2;   // alias: Mpart dead before attn runs

    dim3 blk(256);

    convp2_kernel<<<dim3((TT * (TPAD / 4) + 255) / 256), blk, 0, stream>>>(P, Pbf);

    dim3 g1(TTILES, DD / 64, BB * 3);
    proj5_kernel<<<g1, blk, 0, stream>>>(X, Wq, bq, Wk, bk, Wv, bv, Qb, Kb, Vb);

    dim3 g2(SQN, BEH, NJC);
    ovt7_kernel<<<g2, blk, 0, stream>>>(orth, Vb, Mpart);

    dim3 gr((BEH * DE * (TPAD / 4) + 255) / 256);
    mreduce_kernel<<<gr, blk, 0, stream>>>(Mpart, Mtb);

    dim3 g3(TTILES, BEH, SCN);
    attn5_kernel<<<g3, blk, 0, stream>>>(Qb, Kb, Mtb, Pbf, Hpart);

    dim3 gh((unsigned)((HSTRIDE / 4 + 255) / 256));
    hreduce_kernel<<<gh, blk, 0, stream>>>(Hpart, Hbuf);

    dim3 g4(TTILES, DD / 64, BB * 2);
    oproj2_kernel<<<g4, blk, 0, stream>>>(Hbuf, Wo, opart);

    oreduce_kernel<<<gh, blk, 0, stream>>>(opart, bo, out);
}